// Round 3
// baseline (2214.898 us; speedup 1.0000x reference)
//
#include <hip/hip_runtime.h>
#include <hip/hip_bf16.h>
#include <stdint.h>

#define SEQ   2048
#define EMB   256
#define HHD   256      // per-direction hidden
#define GATES 1024     // 4*HHD
#define NTAGS 12
#define START 10
#define STOP  11
#define CCH   16       // CRF chunks
#define CLEN  128      // steps per chunk

__device__ __forceinline__ int sdot4(uint32_t a, uint32_t b, int c) {
#if __has_builtin(__builtin_amdgcn_sdot4)
  return __builtin_amdgcn_sdot4((int)a, (int)b, c, false);
#else
  int r = c;
#pragma unroll
  for (int i = 0; i < 4; i++) {
    int av = (int)(signed char)((a >> (8 * i)) & 255);
    int bv = (int)(signed char)((b >> (8 * i)) & 255);
    r += av * bv;
  }
  return r;
#endif
}

__device__ __forceinline__ float fsig(float x) {
  float e = __expf(-x);
  return __builtin_amdgcn_rcpf(1.0f + e);
}

// zero-cost pin: forces 16 dwords into addressable (arch) VGPRs at this point
#define PIN16(a, i) asm volatile("" :                                        \
  "+v"(a[i+0]), "+v"(a[i+1]), "+v"(a[i+2]), "+v"(a[i+3]),                    \
  "+v"(a[i+4]), "+v"(a[i+5]), "+v"(a[i+6]), "+v"(a[i+7]),                    \
  "+v"(a[i+8]), "+v"(a[i+9]), "+v"(a[i+10]), "+v"(a[i+11]),                  \
  "+v"(a[i+12]), "+v"(a[i+13]), "+v"(a[i+14]), "+v"(a[i+15]))

// ---------------- 1. Whh fp32 -> int8 rows with per-row scale -----------------------
__global__ __launch_bounds__(256) void k_quant(const float* __restrict__ whh_f,
                                               const float* __restrict__ whh_b,
                                               uint32_t* __restrict__ q4,
                                               float* __restrict__ scales) {
  const int row  = (blockIdx.x * 256 + threadIdx.x) >> 6;  // 0..2047
  const int lane = threadIdx.x & 63;
  const int d = row >> 10, r = row & 1023;
  const float4 w = *(const float4*)((d ? whh_b : whh_f) + (long)r * HHD + lane * 4);
  float m = fmaxf(fmaxf(fabsf(w.x), fabsf(w.y)), fmaxf(fabsf(w.z), fabsf(w.w)));
#pragma unroll
  for (int off = 32; off; off >>= 1) m = fmaxf(m, __shfl_xor(m, off, 64));
  m = fmaxf(m, 1e-20f);
  const float inv = 127.f / m;
  int a = (int)rintf(w.x * inv), b = (int)rintf(w.y * inv);
  int c = (int)rintf(w.z * inv), e = (int)rintf(w.w * inv);
  q4[row * 64 + lane] = (uint32_t)(a & 255) | ((uint32_t)(b & 255) << 8) |
                        ((uint32_t)(c & 255) << 16) | ((uint32_t)(e & 255) << 24);
  if (lane == 0) scales[row] = m / 127.f;
}

// ---------------- 2. input projection: pre[d][t][r] = bih+bhh + Wih @ embed[sent[t]] --
__global__ __launch_bounds__(256) void k_proj(const int* __restrict__ sentence,
                                              const float* __restrict__ embed,
                                              const float* __restrict__ Wih_f,
                                              const float* __restrict__ bih_f,
                                              const float* __restrict__ bhh_f,
                                              const float* __restrict__ Wih_b,
                                              const float* __restrict__ bih_b,
                                              const float* __restrict__ bhh_b,
                                              float* __restrict__ pre) {
  const int dir = blockIdx.y;
  const int t0  = blockIdx.x * 8;
  const float* Wih = dir ? Wih_b : Wih_f;
  const float* bih = dir ? bih_b : bih_f;
  const float* bhh = dir ? bhh_b : bhh_f;

  __shared__ float xs[8][256];
  const int tid = threadIdx.x;
#pragma unroll
  for (int i = 0; i < 8; i++) {
    int s = sentence[t0 + i];
    xs[i][tid] = embed[(long)s * EMB + tid];
  }
  __syncthreads();

  const int r0 = tid * 4;
  float acc[4][8];
#pragma unroll
  for (int j = 0; j < 4; j++)
#pragma unroll
    for (int t = 0; t < 8; t++) acc[j][t] = 0.f;

  const float4* W4 = (const float4*)Wih;
  for (int kq = 0; kq < 64; kq++) {
    float4 w[4];
#pragma unroll
    for (int j = 0; j < 4; j++) w[j] = W4[(r0 + j) * 64 + kq];
#pragma unroll
    for (int t = 0; t < 8; t++) {
      float4 xv = ((const float4*)xs[t])[kq];
#pragma unroll
      for (int j = 0; j < 4; j++)
        acc[j][t] += w[j].x * xv.x + w[j].y * xv.y + w[j].z * xv.z + w[j].w * xv.w;
    }
  }
#pragma unroll
  for (int j = 0; j < 4; j++) {
    float bsum = bih[r0 + j] + bhh[r0 + j];
#pragma unroll
    for (int t = 0; t < 8; t++)
      pre[((long)(dir * SEQ + t0 + t)) * GATES + r0 + j] = acc[j][t] + bsum;
  }
}

// ---------------- 3. sequential LSTM: 1 block/dir, int8 weights pinned in VGPRs ------
// Lane pair (2u, 2u+1) owns hidden unit u. Even lane: gate rows u (i), 256+u (f);
// odd lane: 512+u (g), 768+u (o). 128 weight dwords/lane pinned via PIN16 every step.
__global__ __launch_bounds__(512, 1) void k_lstm(const uint32_t* __restrict__ q4,
                                                 const float* __restrict__ scales,
                                                 const float* __restrict__ pre,
                                                 const float* __restrict__ h0,
                                                 const float* __restrict__ c0,
                                                 float* __restrict__ hs) {
  const int dir = blockIdx.x;
  const int L   = threadIdx.x;
  const int u   = L >> 1;
  const int odd = L & 1;

  __shared__ __align__(16) uint8_t hbuf[2][256];

  const int rA = (odd ? 512 : 0) + u;   // i or g
  const int rB = rA + 256;              // f or o
  const long base = (long)dir * GATES;

  uint32_t w[128];
  {
    const uint4* qq = (const uint4*)q4;
#pragma unroll
    for (int j = 0; j < 16; j++) {
      uint4 v = qq[(base + rA) * 16 + j];
      w[4 * j + 0] = v.x; w[4 * j + 1] = v.y; w[4 * j + 2] = v.z; w[4 * j + 3] = v.w;
    }
#pragma unroll
    for (int j = 0; j < 16; j++) {
      uint4 v = qq[(base + rB) * 16 + j];
      w[64 + 4 * j + 0] = v.x; w[64 + 4 * j + 1] = v.y;
      w[64 + 4 * j + 2] = v.z; w[64 + 4 * j + 3] = v.w;
    }
  }
  const float sA = scales[base + rA];
  const float sB = scales[base + rB];

  // seed h buffer 0 from h0 (scale 4/127: h0 ~ N(0,1), clamp at |4|)
  if (L < 256) {
    float v = h0[dir * HHD + L] * (127.f / 4.f);
    v = fminf(fmaxf(v, -127.f), 127.f);
    hbuf[0][L] = (uint8_t)(int)rintf(v);
  }
  float c_st = c0[dir * HHD + u];
  __syncthreads();

  const float* pd = pre + (long)dir * SEQ * GATES;
  float* hsd      = hs  + (long)dir * SEQ * HHD;
  const float gmul = odd ? 2.f : 1.f;   // tanh(x) = 2*sig(2x)-1 trick, divergence-free

  const long delta = dir ? -(long)GATES : (long)GATES;
  const float* pA = pd + (long)(dir ? SEQ - 1 : 0) * GATES + rA;
  const float* pB = pd + (long)(dir ? SEQ - 1 : 0) * GATES + rB;
  float nxt0 = *pA, nxt1 = *pB;

  for (int s = 0; s < SEQ; s++) {
    // pin the weight file into arch VGPRs for this iteration (0 instructions)
    PIN16(w, 0);  PIN16(w, 16); PIN16(w, 32);  PIN16(w, 48);
    PIN16(w, 64); PIN16(w, 80); PIN16(w, 96);  PIN16(w, 112);

    const int t = dir ? (SEQ - 1 - s) : s;
    const float pre0 = nxt0, pre1 = nxt1;
    if (s + 1 < SEQ) { pA += delta; pB += delta; }
    nxt0 = *pA; nxt1 = *pB;               // prefetch next step under the dot block

    const uint4* hq4 = (const uint4*)hbuf[s & 1];
    int a0 = 0, a1 = 0, b0 = 0, b1 = 0;
#pragma unroll
    for (int cc = 0; cc < 16; cc++) {
      uint4 hq = hq4[cc];
      a0 = sdot4(w[4 * cc + 0], hq.x, a0);
      a1 = sdot4(w[4 * cc + 1], hq.y, a1);
      a0 = sdot4(w[4 * cc + 2], hq.z, a0);
      a1 = sdot4(w[4 * cc + 3], hq.w, a1);
      b0 = sdot4(w[64 + 4 * cc + 0], hq.x, b0);
      b1 = sdot4(w[64 + 4 * cc + 1], hq.y, b1);
      b0 = sdot4(w[64 + 4 * cc + 2], hq.z, b0);
      b1 = sdot4(w[64 + 4 * cc + 3], hq.w, b1);
    }
    const float hsc = (s == 0) ? (4.f / 127.f) : (1.f / 127.f);
    const float g0 = pre0 + sA * hsc * (float)(a0 + a1);  // i (even) | g (odd)
    const float g1 = pre1 + sB * hsc * (float)(b0 + b1);  // f (even) | o (odd)

    // even: v0 = sig(g0)=i ; odd: v0 = 2*sig(2*g0)-1 = tanh(g0)=g. v1 = sig(g1).
    const float v0 = fsig(g0 * gmul) * gmul - (gmul - 1.f);
    const float v1 = fsig(g1);
    const float p0 = __shfl_xor(v0, 1, 64);
    const float p1 = __shfl_xor(v1, 1, 64);
    const float iv = odd ? p0 : v0;
    const float fv = odd ? p1 : v1;
    const float gv = odd ? v0 : p0;
    const float ov = odd ? v1 : p1;

    c_st = fv * c_st + iv * gv;
    const float hv = ov * (2.f * fsig(2.f * c_st) - 1.f);

    if (!odd) {
      hsd[(long)t * HHD + u] = hv;
    } else {
      hbuf[(s + 1) & 1][u] = (uint8_t)(int)rintf(hv * 127.f);  // |hv|<1
    }
    __syncthreads();
  }
}

// ---------------- 4. feats[t][n] = b_out[n] + W_out[n] . [hf[t]; hb[t]] --------------
__global__ __launch_bounds__(192) void k_feats(const float* __restrict__ hs,
                                               const float* __restrict__ W_out,
                                               const float* __restrict__ b_out,
                                               float* __restrict__ feats) {
  __shared__ float Wl[12 * 520];
  const int tid = threadIdx.x;
  for (int i = tid; i < 12 * 512; i += 192) Wl[(i / 512) * 520 + (i % 512)] = W_out[i];
  __syncthreads();

  const int tl = tid / 12, n = tid % 12;
  const int t = blockIdx.x * 16 + tl;
  const float4* hf4 = (const float4*)(hs + (long)t * HHD);
  const float4* hb4 = (const float4*)(hs + (long)SEQ * HHD + (long)t * HHD);
  const float4* Wa  = (const float4*)&Wl[n * 520];
  const float4* Wb  = (const float4*)&Wl[n * 520 + 256];

  float acc = b_out[n];
#pragma unroll 8
  for (int j = 0; j < 64; j++) {
    float4 w = Wa[j], h = hf4[j];
    acc += w.x * h.x + w.y * h.y + w.z * h.z + w.w * h.w;
  }
#pragma unroll 8
  for (int j = 0; j < 64; j++) {
    float4 w = Wb[j], h = hb4[j];
    acc += w.x * h.x + w.y * h.y + w.z * h.z + w.w * h.w;
  }
  feats[t * NTAGS + n] = acc;
}

// ---------------- 5a. CRF chunk: fold 128 steps into a 12x12 log-semiring matrix -----
__global__ __launch_bounds__(192) void k_crf_chunk(const float* __restrict__ feats,
                                                   const float* __restrict__ trans,
                                                   float* __restrict__ Pc) {
  const int ch  = blockIdx.x;
  const int tid = threadIdx.x;
  const int n   = tid & 15;
  const int p   = tid >> 4;                // 0..11
  const int nn  = (n < 12) ? n : 11;

  __shared__ float fe[CLEN * NTAGS];
  for (int i = tid; i < CLEN * NTAGS; i += 192) fe[i] = feats[ch * CLEN * NTAGS + i];
  __syncthreads();

  float trn[12];
#pragma unroll
  for (int j = 0; j < 12; j++) trn[j] = trans[nn * 12 + j];

  float Mv = trans[nn * 12 + p] + fe[nn];  // A_{t0}[n,p]
  for (int t = 1; t < CLEN; t++) {
    float x[12], m = -1e30f;
#pragma unroll
    for (int j = 0; j < 12; j++) {
      x[j] = trn[j] + __shfl(Mv, (tid & 48) | j, 64);
      m = fmaxf(m, x[j]);
    }
    float ss = 0.f;
#pragma unroll
    for (int j = 0; j < 12; j++) ss += __expf(x[j] - m);
    Mv = fe[t * NTAGS + nn] + m + __logf(ss);
  }
  if (n < 12) Pc[ch * 144 + n * 12 + p] = Mv;
}

// ---------------- 5b. combine chunk matrices + stop + gold score ---------------------
__global__ __launch_bounds__(128) void k_crf_final(const float* __restrict__ Pc,
                                                   const float* __restrict__ feats,
                                                   const int* __restrict__ tags,
                                                   const float* __restrict__ trans,
                                                   float* __restrict__ out) {
  __shared__ float Pl[CCH * 144];
  __shared__ float res[2];
  const int tid = threadIdx.x;
  for (int i = tid; i < CCH * 144; i += 128) Pl[i] = Pc[i];
  __syncthreads();

  if (tid < 64) {
    const int n  = tid;
    const int nn = (n < 12) ? n : 11;
    float fv = (n == START) ? 0.f : -10000.f;
    for (int c = 0; c < CCH; c++) {
      float x[12], m = -1e30f;
#pragma unroll
      for (int j = 0; j < 12; j++) {
        x[j] = Pl[c * 144 + nn * 12 + j] + __shfl(fv, j, 64);
        m = fmaxf(m, x[j]);
      }
      float ss = 0.f;
#pragma unroll
      for (int j = 0; j < 12; j++) ss += __expf(x[j] - m);
      fv = m + __logf(ss);
    }
    const float v = fv + trans[STOP * 12 + nn];
    float xs[12], m = -1e30f;
#pragma unroll
    for (int j = 0; j < 12; j++) {
      xs[j] = __shfl(v, j, 64);
      m = fmaxf(m, xs[j]);
    }
    float ss = 0.f;
#pragma unroll
    for (int j = 0; j < 12; j++) ss += __expf(xs[j] - m);
    if (tid == 0) res[0] = m + __logf(ss);
  } else {
    const int i = tid - 64;
    float gp = 0.f;
    for (int b = 0; b < 32; b++) {
      int t  = b * 64 + i;
      int tg = tags[t];
      int pv = (t == 0) ? START : tags[t - 1];
      gp += trans[tg * 12 + pv] + feats[t * NTAGS + tg];
    }
#pragma unroll
    for (int off = 32; off; off >>= 1) gp += __shfl_xor(gp, off, 64);
    if (i == 0) res[1] = gp + trans[STOP * 12 + tags[SEQ - 1]];
  }
  __syncthreads();
  if (tid == 0) out[0] = res[0] - res[1];
}

// -------------------------------------------------------------------------------------
extern "C" void kernel_launch(void* const* d_in, const int* in_sizes, int n_in,
                              void* d_out, int out_size, void* d_ws, size_t ws_size,
                              hipStream_t stream) {
  const int*   sentence = (const int*)  d_in[0];
  const int*   tags     = (const int*)  d_in[1];
  const float* embed    = (const float*)d_in[2];
  const float* Wih_f    = (const float*)d_in[3];
  const float* Whh_f    = (const float*)d_in[4];
  const float* bih_f    = (const float*)d_in[5];
  const float* bhh_f    = (const float*)d_in[6];
  const float* Wih_b    = (const float*)d_in[7];
  const float* Whh_b    = (const float*)d_in[8];
  const float* bih_b    = (const float*)d_in[9];
  const float* bhh_b    = (const float*)d_in[10];
  const float* W_out    = (const float*)d_in[11];
  const float* b_out    = (const float*)d_in[12];
  const float* h0       = (const float*)d_in[13];
  const float* c0       = (const float*)d_in[14];
  const float* trans    = (const float*)d_in[15];
  float* out = (float*)d_out;

  char* ws = (char*)d_ws;
  uint32_t* q4    = (uint32_t*)ws;                          // 512 KB
  float*    scales= (float*)(ws + (512l << 10));            // 8 KB
  float*    pre   = (float*)(ws + (1l  << 20));             // 16 MB : pre[2][2048][1024]
  float*    hs    = (float*)(ws + (17l << 20));             // 4 MB  : hs[2][2048][256]
  float*    feats = (float*)(ws + (21l << 20));             // 96 KB : feats[2048][12]
  float*    Pc    = (float*)(ws + (21l << 20) + (128l<<10));// 9 KB  : Pc[16][12][12]

  k_quant<<<512, 256, 0, stream>>>(Whh_f, Whh_b, q4, scales);
  k_proj<<<dim3(256, 2), 256, 0, stream>>>(sentence, embed, Wih_f, bih_f, bhh_f,
                                           Wih_b, bih_b, bhh_b, pre);
  k_lstm<<<2, 512, 0, stream>>>(q4, scales, pre, h0, c0, hs);
  k_feats<<<128, 192, 0, stream>>>(hs, W_out, b_out, feats);
  k_crf_chunk<<<CCH, 192, 0, stream>>>(feats, trans, Pc);
  k_crf_final<<<1, 128, 0, stream>>>(Pc, feats, tags, trans, out);
}